// Round 2
// baseline (195.067 us; speedup 1.0000x reference)
//
#include <hip/hip_runtime.h>
#include <cstdint>
#include <cstddef>

#define CIN   256
#define COUT  128

typedef float  f32x4  __attribute__((ext_vector_type(4)));
typedef __bf16 bf16x8 __attribute__((ext_vector_type(8)));

// ---------------- workspace layout (bytes) ----------------
#define XPAD_BYTES (16ull*66*66*256*2)          // 35,684,352  bf16 padded x
#define WT_OFF     XPAD_BYTES
#define WT_BYTES   (16ull*128*256*2)            // 1,048,576   bf16 w, [tap][co][ci]
#define SPAD_OFF   (WT_OFF + WT_BYTES)
#define SPAD_BYTES (16ull*66*66*4)              // 278,784     fp32 per-pixel sum(x^2)
#define KSQ_OFF    (SPAD_OFF + SPAD_BYTES)
#define WS_NEEDED  (KSQ_OFF + 512)

__device__ __forceinline__ unsigned short f2bf(float f) {
  unsigned int u = __float_as_uint(f);
  u += 0x7fffu + ((u >> 16) & 1u);              // RNE
  return (unsigned short)(u >> 16);
}

__device__ __forceinline__ void async16(const void* lds, const void* g) {
  __builtin_amdgcn_global_load_lds(
      (const __attribute__((address_space(1))) unsigned int*)g,
      (__attribute__((address_space(3))) unsigned int*)lds, 16, 0, 0);
}

// ---------------- prep: pad+convert x, channel sum of x^2 ----------------
__global__ __launch_bounds__(256) void prep_x(
    const float* __restrict__ x, unsigned short* __restrict__ xpad,
    float* __restrict__ spad)
{
  int wave = threadIdx.x >> 6, lane = threadIdx.x & 63;
  int p = blockIdx.x * 4 + wave;                 // 0..69695 over [16][66][66]
  int b = p / 4356;
  int rem = p - b * 4356;
  int iyp = rem / 66, ixp = rem - iyp * 66;
  bool interior = (iyp >= 1 && iyp <= 64 && ixp >= 1 && ixp <= 64);
  f32x4 v = {0.f, 0.f, 0.f, 0.f};
  if (interior) {
    const float* src = x + (((size_t)b*64 + (iyp-1))*64 + (ixp-1))*CIN + lane*4;
    v = *(const f32x4*)src;
  }
  ushort4 h;
  h.x = f2bf(v.x); h.y = f2bf(v.y); h.z = f2bf(v.z); h.w = f2bf(v.w);
  *(ushort4*)(xpad + (size_t)p*CIN + lane*4) = h;
  float s = v.x*v.x + v.y*v.y + v.z*v.z + v.w*v.w;
  #pragma unroll
  for (int off = 32; off > 0; off >>= 1) s += __shfl_down(s, off);
  if (lane == 0) spad[p] = s;
}

// ---------------- prep: transpose+convert w, k_sq ----------------
__global__ __launch_bounds__(256) void prep_w(
    const float* __restrict__ w, unsigned short* __restrict__ wt,
    float* __restrict__ ksq)
{
  __shared__ __align__(16) unsigned short lw[32*128];
  __shared__ f32x4 red[256];
  int t = threadIdx.x;
  int tap = blockIdx.x >> 3;
  int ci0 = (blockIdx.x & 7) * 32;
  f32x4 sq = {0.f, 0.f, 0.f, 0.f};
  int co4 = (t & 31) * 4;
  #pragma unroll
  for (int i = 0; i < 4; ++i) {
    int ci = (t >> 5) + i*8;
    const float* src = w + ((size_t)(tap*256 + ci0 + ci))*COUT + co4;
    f32x4 v = *(const f32x4*)src;
    sq.x += v.x*v.x; sq.y += v.y*v.y; sq.z += v.z*v.z; sq.w += v.w*v.w;
    ushort4 h; h.x = f2bf(v.x); h.y = f2bf(v.y); h.z = f2bf(v.z); h.w = f2bf(v.w);
    *(ushort4*)&lw[ci*128 + co4] = h;
  }
  red[t] = sq;
  __syncthreads();
  if (t < 32) {
    f32x4 tot = red[t];
    #pragma unroll
    for (int j = 1; j < 8; ++j) {
      f32x4 o = red[t + 32*j];
      tot.x += o.x; tot.y += o.y; tot.z += o.z; tot.w += o.w;
    }
    atomicAdd(ksq + t*4 + 0, tot.x);
    atomicAdd(ksq + t*4 + 1, tot.y);
    atomicAdd(ksq + t*4 + 2, tot.z);
    atomicAdd(ksq + t*4 + 3, tot.w);
  }
  // write wt[tap][co][ci0..ci0+32)
  int co = t >> 1, h16 = (t & 1) * 16;
  union { unsigned short u[16]; uint4 q[2]; } tmp;
  #pragma unroll
  for (int i = 0; i < 16; ++i) tmp.u[i] = lw[(h16 + i)*128 + co];
  uint4* dst = (uint4*)(wt + ((size_t)tap*128 + co)*CIN + ci0 + h16);
  dst[0] = tmp.q[0]; dst[1] = tmp.q[1];
}

// ---------------- main fused kernel ----------------
// grid = 2048 (XCD-swizzled): bid -> b = bid>>7, u = (bid>>1)&63, py = bid&1
// block = 256 (4 waves): wave = (px<<1)|coh, wave tile = 64 v x 64 co
// LDS A layout: xs[buf][(a*4 + q)*66 + c][8]  (q = k-octet) -> conflict-free
// B fragments: direct global->VGPR (weights are L2-resident)
__global__ __launch_bounds__(256) void yat_main(
    const unsigned short* __restrict__ xpad,
    const unsigned short* __restrict__ wt,
    const float* __restrict__ spad,
    const float* __restrict__ ksq,
    const float* __restrict__ bias,
    const float* __restrict__ alpha,
    float* __restrict__ out)
{
  __shared__ __align__(16) unsigned short xs[2][4224];   // 2 x 8448 B
  __shared__ float srow[132];

  int orig = blockIdx.x;
  int bid = (orig & 7) * 256 + (orig >> 3);              // XCD-contiguous
  int py = bid & 1, u = (bid >> 1) & 63, b = bid >> 7;
  int t = threadIdx.x, wave = t >> 6, lane = t & 63;
  int px = wave >> 1, coh = wave & 1;
  int l15 = lane & 15, l4 = lane >> 4;

  if (t < 132) {
    int r = t / 66, c = t - r*66;
    srow[t] = spad[((size_t)b*66 + (u + py) + r)*66 + c];
  }

  const size_t xrow = ((size_t)b*66 + (u + py)) * 66 * CIN;

  // precompute per-thread stage source offsets (chunk-invariant part)
  size_t soff0, soff1, tailoff = 0;
  {
    int s = t;                                   // i = 0
    int a = s / 264; int r2 = s - a*264;
    int q = r2 / 66; int c = r2 - q*66;
    soff0 = xrow + (size_t)(a*66 + c)*CIN + q*8;
    s = 256 + t;                                 // i = 1
    a = s / 264; r2 = s - a*264;
    q = r2 / 66; c = r2 - q*66;
    soff1 = xrow + (size_t)(a*66 + c)*CIN + q*8;
  }
  if (t < 16) {
    int s2 = 248 + t;                            // a = 1 tail segs 512..527
    int q = s2 / 66, c = s2 - q*66;
    tailoff = xrow + (size_t)(66 + c)*CIN + q*8;
  }

  // per-lane bases
  const unsigned short* abase = &xs[0][((size_t)l4*66 + l15 + px)*8];
  // B: wt[((py+2a)*4 + px+2bb)*128 + coh*64 + nt*16 + l15][ci0 + l4*8]
  const unsigned short* wb =
      wt + ((size_t)((py*4 + px)*128 + coh*64 + l15))*CIN + l4*8;

  f32x4 acc[4][4];
  #pragma unroll
  for (int i = 0; i < 4; ++i)
    #pragma unroll
    for (int j = 0; j < 4; ++j)
      acc[i][j] = (f32x4){0.f, 0.f, 0.f, 0.f};

  // prologue: stage chunk 0 into buf 0
  async16(&xs[0][(0*256 + wave*64)*8], xpad + soff0);
  async16(&xs[0][(1*256 + wave*64)*8], xpad + soff1);
  if (t < 16) *(uint4*)&xs[0][(512 + t)*8] = *(const uint4*)(xpad + tailoff);
  __syncthreads();

  #pragma unroll
  for (int c8 = 0; c8 < 8; ++c8) {
    const int buf = c8 & 1;
    const int ci0 = c8 * 32;

    // B fragments for this chunk: 16 direct global loads (L2-resident)
    bf16x8 Bf[2][2][4];                                  // [a][bb][nt]
    #pragma unroll
    for (int a = 0; a < 2; ++a)
      #pragma unroll
      for (int bb = 0; bb < 2; ++bb)
        #pragma unroll
        for (int nt = 0; nt < 4; ++nt)
          Bf[a][bb][nt] = *(const bf16x8*)(
              wb + ((size_t)((2*a*4 + 2*bb)*128 + nt*16))*CIN + ci0);

    // stage chunk c8+1 into the other buffer (async, drains at barrier)
    if (c8 < 7) {
      const int nb = buf ^ 1;
      const int nci = ci0 + 32;
      async16(&xs[nb][(0*256 + wave*64)*8], xpad + soff0 + nci);
      async16(&xs[nb][(1*256 + wave*64)*8], xpad + soff1 + nci);
      if (t < 16) *(uint4*)&xs[nb][(512 + t)*8] =
          *(const uint4*)(xpad + tailoff + nci);
    }

    // compute: A from LDS (conflict-free), B from VGPR
    #pragma unroll
    for (int a = 0; a < 2; ++a) {
      bf16x8 Af[2][4];                                   // [bb][mt]
      #pragma unroll
      for (int bb = 0; bb < 2; ++bb)
        #pragma unroll
        for (int mt = 0; mt < 4; ++mt)
          Af[bb][mt] = *(const bf16x8*)(
              abase + (size_t)buf*4224 + (size_t)(a*4*66 + mt*16 + bb)*8);
      #pragma unroll
      for (int bb = 0; bb < 2; ++bb)
        #pragma unroll
        for (int mt = 0; mt < 4; ++mt)
          #pragma unroll
          for (int nt = 0; nt < 4; ++nt)
            acc[mt][nt] = __builtin_amdgcn_mfma_f32_16x16x32_bf16(
                Af[bb][mt], Bf[a][bb][nt], acc[mt][nt], 0, 0, 0);
    }
    __syncthreads();
  }

  // ---------------- epilogue ----------------
  float scale = powf(sqrtf(128.f) / log1pf(128.f), alpha[0]);
  int oy = 2*u + py;
  float kq[4], bi[4];
  #pragma unroll
  for (int nt = 0; nt < 4; ++nt) {
    int n = coh*64 + nt*16 + l15;
    kq[nt] = ksq[n]; bi[nt] = bias[n];
  }
  size_t orow = ((size_t)b*128 + oy) * 128 * COUT;
  #pragma unroll
  for (int mt = 0; mt < 4; ++mt) {
    #pragma unroll
    for (int r = 0; r < 4; ++r) {
      int v = mt*16 + l4*4 + r;
      float ps = srow[v+px] + srow[v+px+1] + srow[66 + v+px] + srow[66 + v+px+1];
      #pragma unroll
      for (int nt = 0; nt < 4; ++nt) {
        float dot = acc[mt][nt][r];
        float dist = ps + kq[nt] - 2.f*dot + 1e-5f;
        float y = (dot*dot/dist + bi[nt]) * scale;
        int n = coh*64 + nt*16 + l15;
        out[orow + (size_t)(2*v + px)*COUT + n] = y;
      }
    }
  }
}

// ---------------- fallback (tiny ws): direct fp32 ----------------
__global__ __launch_bounds__(256) void fb_ksq(const float* __restrict__ w,
                                              float* __restrict__ ksq) {
  __shared__ float red[256];
  int co = blockIdx.x, t = threadIdx.x;
  float s = 0.f;
  for (int j = t; j < 4096; j += 256) { float v = w[(size_t)j*COUT + co]; s += v*v; }
  red[t] = s; __syncthreads();
  for (int off = 128; off > 0; off >>= 1) {
    if (t < off) red[t] += red[t + off];
    __syncthreads();
  }
  if (t == 0) ksq[co] = red[0];
}

__global__ __launch_bounds__(256) void fb_main(
    const float* __restrict__ x, const float* __restrict__ w,
    const float* __restrict__ bias, const float* __restrict__ alpha,
    const float* __restrict__ ksq, float* __restrict__ out)
{
  size_t idx = (size_t)blockIdx.x * 256 + threadIdx.x;
  int co = (int)(idx & 127);
  int ox = (int)((idx >> 7) & 127);
  int oy = (int)((idx >> 14) & 127);
  int b  = (int)(idx >> 21);
  int py = oy & 1, px = ox & 1, u = oy >> 1, v = ox >> 1;
  float dot = 0.f, ps = 0.f;
  for (int a = 0; a < 2; ++a) {
    int iy = u + py + a - 1;
    if (iy < 0 || iy > 63) continue;
    for (int b2 = 0; b2 < 2; ++b2) {
      int ix = v + px + b2 - 1;
      if (ix < 0 || ix > 63) continue;
      const float* xp = x + (((size_t)b*64 + iy)*64 + ix)*CIN;
      const float* wp = w + ((size_t)((py + 2*a)*4 + (px + 2*b2))*CIN)*COUT + co;
      for (int ci = 0; ci < CIN; ++ci) {
        float xv = xp[ci];
        dot += xv * wp[(size_t)ci*COUT];
        ps  += xv * xv;
      }
    }
  }
  float dist = ps + ksq[co] - 2.f*dot + 1e-5f;
  float scale = powf(sqrtf(128.f) / log1pf(128.f), alpha[0]);
  out[idx] = (dot*dot/dist + bias[co]) * scale;
}

// ---------------- launcher ----------------
extern "C" void kernel_launch(void* const* d_in, const int* in_sizes, int n_in,
                              void* d_out, int out_size, void* d_ws, size_t ws_size,
                              hipStream_t stream)
{
  const float* x     = (const float*)d_in[0];
  const float* w     = (const float*)d_in[1];
  const float* bias  = (const float*)d_in[2];
  const float* alpha = (const float*)d_in[3];
  float* out = (float*)d_out;

  if (ws_size < WS_NEEDED) {
    float* ksq = (float*)d_ws;
    fb_ksq<<<128, 256, 0, stream>>>(w, ksq);
    fb_main<<<131072, 256, 0, stream>>>(x, w, bias, alpha, ksq, out);
    return;
  }

  unsigned short* xpad = (unsigned short*)d_ws;
  unsigned short* wtp  = (unsigned short*)((char*)d_ws + WT_OFF);
  float* spad = (float*)((char*)d_ws + SPAD_OFF);
  float* ksq  = (float*)((char*)d_ws + KSQ_OFF);

  hipMemsetAsync(ksq, 0, 512, stream);
  prep_x<<<17424, 256, 0, stream>>>(x, xpad, spad);
  prep_w<<<128, 256, 0, stream>>>(w, wtp, ksq);
  yat_main<<<2048, 256, 0, stream>>>(xpad, wtp, spad, ksq, bias, alpha, out);
}

// Round 4
// 188.527 us; speedup vs baseline: 1.0347x; 1.0347x over previous
//
#include <hip/hip_runtime.h>
#include <cstdint>
#include <cstddef>

#define CIN   256
#define COUT  128

typedef float  f32x4  __attribute__((ext_vector_type(4)));
typedef __bf16 bf16x8 __attribute__((ext_vector_type(8)));

// ---------------- workspace layout (bytes) ----------------
#define XPAD_BYTES (16ull*66*66*256*2)          // 35,684,352  bf16 padded x
#define WT_OFF     XPAD_BYTES
#define WT_BYTES   (16ull*128*256*2)            // 1,048,576   bf16 w, [tap][co][ci]
#define SPAD_OFF   (WT_OFF + WT_BYTES)
#define SPAD_BYTES (16ull*66*66*4)              // 278,784     fp32 per-pixel sum(x^2)
#define KSQ_OFF    (SPAD_OFF + SPAD_BYTES)
#define WS_NEEDED  (KSQ_OFF + 512)

__device__ __forceinline__ unsigned short f2bf(float f) {
  unsigned int u = __float_as_uint(f);
  u += 0x7fffu + ((u >> 16) & 1u);              // RNE
  return (unsigned short)(u >> 16);
}

__device__ __forceinline__ void async16(const void* lds, const void* g) {
  __builtin_amdgcn_global_load_lds(
      (const __attribute__((address_space(1))) unsigned int*)g,
      (__attribute__((address_space(3))) unsigned int*)lds, 16, 0, 0);
}

// ---------------- prep: pad+convert x, channel sum of x^2 ----------------
__global__ __launch_bounds__(256) void prep_x(
    const float* __restrict__ x, unsigned short* __restrict__ xpad,
    float* __restrict__ spad)
{
  int wave = threadIdx.x >> 6, lane = threadIdx.x & 63;
  int p = blockIdx.x * 4 + wave;                 // 0..69695 over [16][66][66]
  int b = p / 4356;
  int rem = p - b * 4356;
  int iyp = rem / 66, ixp = rem - iyp * 66;
  bool interior = (iyp >= 1 && iyp <= 64 && ixp >= 1 && ixp <= 64);
  f32x4 v = {0.f, 0.f, 0.f, 0.f};
  if (interior) {
    const float* src = x + (((size_t)b*64 + (iyp-1))*64 + (ixp-1))*CIN + lane*4;
    v = *(const f32x4*)src;
  }
  ushort4 h;
  h.x = f2bf(v.x); h.y = f2bf(v.y); h.z = f2bf(v.z); h.w = f2bf(v.w);
  *(ushort4*)(xpad + (size_t)p*CIN + lane*4) = h;
  float s = v.x*v.x + v.y*v.y + v.z*v.z + v.w*v.w;
  #pragma unroll
  for (int off = 32; off > 0; off >>= 1) s += __shfl_down(s, off);
  if (lane == 0) spad[p] = s;
}

// ---------------- prep: transpose+convert w, k_sq ----------------
__global__ __launch_bounds__(256) void prep_w(
    const float* __restrict__ w, unsigned short* __restrict__ wt,
    float* __restrict__ ksq)
{
  __shared__ __align__(16) unsigned short lw[32*128];
  __shared__ f32x4 red[256];
  int t = threadIdx.x;
  int tap = blockIdx.x >> 3;
  int ci0 = (blockIdx.x & 7) * 32;
  f32x4 sq = {0.f, 0.f, 0.f, 0.f};
  int co4 = (t & 31) * 4;
  #pragma unroll
  for (int i = 0; i < 4; ++i) {
    int ci = (t >> 5) + i*8;
    const float* src = w + ((size_t)(tap*256 + ci0 + ci))*COUT + co4;
    f32x4 v = *(const f32x4*)src;
    sq.x += v.x*v.x; sq.y += v.y*v.y; sq.z += v.z*v.z; sq.w += v.w*v.w;
    ushort4 h; h.x = f2bf(v.x); h.y = f2bf(v.y); h.z = f2bf(v.z); h.w = f2bf(v.w);
    *(ushort4*)&lw[ci*128 + co4] = h;
  }
  red[t] = sq;
  __syncthreads();
  if (t < 32) {
    f32x4 tot = red[t];
    #pragma unroll
    for (int j = 1; j < 8; ++j) {
      f32x4 o = red[t + 32*j];
      tot.x += o.x; tot.y += o.y; tot.z += o.z; tot.w += o.w;
    }
    atomicAdd(ksq + t*4 + 0, tot.x);
    atomicAdd(ksq + t*4 + 1, tot.y);
    atomicAdd(ksq + t*4 + 2, tot.z);
    atomicAdd(ksq + t*4 + 3, tot.w);
  }
  int co = t >> 1, h16 = (t & 1) * 16;
  union { unsigned short u[16]; uint4 q[2]; } tmp;
  #pragma unroll
  for (int i = 0; i < 16; ++i) tmp.u[i] = lw[(h16 + i)*128 + co];
  uint4* dst = (uint4*)(wt + ((size_t)tap*128 + co)*CIN + ci0 + h16);
  dst[0] = tmp.q[0]; dst[1] = tmp.q[1];
}

// ---------------- main fused kernel ----------------
// grid = 2048 (XCD-swizzled): bid -> b = bid>>7, u = (bid>>1)&63, py = bid&1
// block = 256 (4 waves): wave = (px<<1)|coh, wave tile = 64 v x 64 co
// R2 skeleton + ONE change: B fragments register-double-buffered at full-chunk
// distance (loads for chunk c+1 issue at top of chunk c -> L2 latency hidden
// under c's ds_read+MFMA; compiler's counted vmcnt keeps them in flight
// across the barrier).
__global__ __launch_bounds__(256, 2) void yat_main(
    const unsigned short* __restrict__ xpad,
    const unsigned short* __restrict__ wt,
    const float* __restrict__ spad,
    const float* __restrict__ ksq,
    const float* __restrict__ bias,
    const float* __restrict__ alpha,
    float* __restrict__ out)
{
  __shared__ __align__(16) unsigned short xs[2][4224];   // 2 x 8448 B
  __shared__ float srow[132];

  int orig = blockIdx.x;
  int bid = (orig & 7) * 256 + (orig >> 3);              // XCD-contiguous
  int py = bid & 1, u = (bid >> 1) & 63, b = bid >> 7;
  int t = threadIdx.x, wave = t >> 6, lane = t & 63;
  int px = wave >> 1, coh = wave & 1;
  int l15 = lane & 15, l4 = lane >> 4;

  if (t < 132) {
    int r = t / 66, c = t - r*66;
    srow[t] = spad[((size_t)b*66 + (u + py) + r)*66 + c];
  }

  const size_t xrow = ((size_t)b*66 + (u + py)) * 66 * CIN;

  // per-thread stage source offsets (chunk-invariant part)
  size_t soff0, soff1, tailoff = 0;
  {
    int s = t;                                   // i = 0
    int a = s / 264; int r2 = s - a*264;
    int q = r2 / 66; int c = r2 - q*66;
    soff0 = xrow + (size_t)(a*66 + c)*CIN + q*8;
    s = 256 + t;                                 // i = 1
    a = s / 264; r2 = s - a*264;
    q = r2 / 66; c = r2 - q*66;
    soff1 = xrow + (size_t)(a*66 + c)*CIN + q*8;
  }
  if (t < 16) {
    int s2 = 248 + t;                            // a = 1 tail segs 512..527
    int q = s2 / 66, c = s2 - q*66;
    tailoff = xrow + (size_t)(66 + c)*CIN + q*8;
  }

  const unsigned short* abase = &xs[0][((size_t)l4*66 + l15 + px)*8];
  const unsigned short* wb =
      wt + ((size_t)((py*4 + px)*128 + coh*64 + l15))*CIN + l4*8;

  f32x4 acc[4][4];
  #pragma unroll
  for (int i = 0; i < 4; ++i)
    #pragma unroll
    for (int j = 0; j < 4; ++j)
      acc[i][j] = (f32x4){0.f, 0.f, 0.f, 0.f};

  bf16x8 Bf[2][2][2][4];                                 // [parity][a][bb][nt]

#define STAGE_CHUNK(NB, CI0)                                               \
  {                                                                        \
    async16(&xs[NB][(size_t)(0*256 + wave*64)*8], xpad + soff0 + (CI0));   \
    async16(&xs[NB][(size_t)(1*256 + wave*64)*8], xpad + soff1 + (CI0));   \
    if (t < 16) *(uint4*)&xs[NB][(size_t)(512 + t)*8] =                    \
        *(const uint4*)(xpad + tailoff + (CI0));                           \
  }

#define LOAD_B(P, CI0)                                                     \
  {                                                                        \
    _Pragma("unroll")                                                      \
    for (int a = 0; a < 2; ++a)                                            \
      _Pragma("unroll")                                                    \
      for (int bb = 0; bb < 2; ++bb)                                       \
        _Pragma("unroll")                                                  \
        for (int nt = 0; nt < 4; ++nt)                                     \
          Bf[P][a][bb][nt] = *(const bf16x8*)(                             \
              wb + ((size_t)((8*a + 2*bb)*128 + nt*16))*CIN + (CI0));      \
  }

  // prologue: stage chunk 0 into buf 0; load B parity 0 (ci0 = 0)
  STAGE_CHUNK(0, 0);
  LOAD_B(0, 0);
  __syncthreads();

  #pragma unroll
  for (int c8 = 0; c8 < 8; ++c8) {
    const int buf = c8 & 1;                              // also B parity
    if (c8 < 7) {
      STAGE_CHUNK(buf ^ 1, (c8 + 1) * 32);
      LOAD_B(buf ^ 1, (c8 + 1) * 32);
    }
    // compute: A from LDS (conflict-free), B from parity buffer loaded
    // one full chunk ago
    #pragma unroll
    for (int a = 0; a < 2; ++a) {
      bf16x8 Af[2][4];                                   // [bb][mt]
      #pragma unroll
      for (int bb = 0; bb < 2; ++bb)
        #pragma unroll
        for (int mt = 0; mt < 4; ++mt)
          Af[bb][mt] = *(const bf16x8*)(
              abase + (size_t)buf*4224 + (size_t)(a*264 + mt*16 + bb)*8);
      #pragma unroll
      for (int bb = 0; bb < 2; ++bb)
        #pragma unroll
        for (int mt = 0; mt < 4; ++mt)
          #pragma unroll
          for (int nt = 0; nt < 4; ++nt)
            acc[mt][nt] = __builtin_amdgcn_mfma_f32_16x16x32_bf16(
                Af[bb][mt], Bf[buf][a][bb][nt], acc[mt][nt], 0, 0, 0);
    }
    __syncthreads();
  }

#undef STAGE_CHUNK
#undef LOAD_B

  // ---------------- epilogue ----------------
  float scale = powf(sqrtf(128.f) / log1pf(128.f), alpha[0]);
  int oy = 2*u + py;
  float kq[4], bi[4];
  #pragma unroll
  for (int nt = 0; nt < 4; ++nt) {
    int n = coh*64 + nt*16 + l15;
    kq[nt] = ksq[n]; bi[nt] = bias[n];
  }
  size_t orow = ((size_t)b*128 + oy) * 128 * COUT;
  #pragma unroll
  for (int mt = 0; mt < 4; ++mt) {
    #pragma unroll
    for (int r = 0; r < 4; ++r) {
      int v = mt*16 + l4*4 + r;
      float ps = srow[v+px] + srow[v+px+1] + srow[66 + v+px] + srow[66 + v+px+1];
      #pragma unroll
      for (int nt = 0; nt < 4; ++nt) {
        float dot = acc[mt][nt][r];
        float dist = ps + kq[nt] - 2.f*dot + 1e-5f;
        float y = (dot*dot/dist + bi[nt]) * scale;
        int n = coh*64 + nt*16 + l15;
        out[orow + (size_t)(2*v + px)*COUT + n] = y;
      }
    }
  }
}

// ---------------- fallback (tiny ws): direct fp32 ----------------
__global__ __launch_bounds__(256) void fb_ksq(const float* __restrict__ w,
                                              float* __restrict__ ksq) {
  __shared__ float red[256];
  int co = blockIdx.x, t = threadIdx.x;
  float s = 0.f;
  for (int j = t; j < 4096; j += 256) { float v = w[(size_t)j*COUT + co]; s += v*v; }
  red[t] = s; __syncthreads();
  for (int off = 128; off > 0; off >>= 1) {
    if (t < off) red[t] += red[t + off];
    __syncthreads();
  }
  if (t == 0) ksq[co] = red[0];
}

__global__ __launch_bounds__(256) void fb_main(
    const float* __restrict__ x, const float* __restrict__ w,
    const float* __restrict__ bias, const float* __restrict__ alpha,
    const float* __restrict__ ksq, float* __restrict__ out)
{
  size_t idx = (size_t)blockIdx.x * 256 + threadIdx.x;
  int co = (int)(idx & 127);
  int ox = (int)((idx >> 7) & 127);
  int oy = (int)((idx >> 14) & 127);
  int b  = (int)(idx >> 21);
  int py = oy & 1, px = ox & 1, u = oy >> 1, v = ox >> 1;
  float dot = 0.f, ps = 0.f;
  for (int a = 0; a < 2; ++a) {
    int iy = u + py + a - 1;
    if (iy < 0 || iy > 63) continue;
    for (int b2 = 0; b2 < 2; ++b2) {
      int ix = v + px + b2 - 1;
      if (ix < 0 || ix > 63) continue;
      const float* xp = x + (((size_t)b*64 + iy)*64 + ix)*CIN;
      const float* wp = w + ((size_t)((py + 2*a)*4 + (px + 2*b2))*CIN)*COUT + co;
      for (int ci = 0; ci < CIN; ++ci) {
        float xv = xp[ci];
        dot += xv * wp[(size_t)ci*COUT];
        ps  += xv * xv;
      }
    }
  }
  float dist = ps + ksq[co] - 2.f*dot + 1e-5f;
  float scale = powf(sqrtf(128.f) / log1pf(128.f), alpha[0]);
  out[idx] = (dot*dot/dist + bias[co]) * scale;
}

// ---------------- launcher ----------------
extern "C" void kernel_launch(void* const* d_in, const int* in_sizes, int n_in,
                              void* d_out, int out_size, void* d_ws, size_t ws_size,
                              hipStream_t stream)
{
  const float* x     = (const float*)d_in[0];
  const float* w     = (const float*)d_in[1];
  const float* bias  = (const float*)d_in[2];
  const float* alpha = (const float*)d_in[3];
  float* out = (float*)d_out;

  if (ws_size < WS_NEEDED) {
    float* ksq = (float*)d_ws;
    fb_ksq<<<128, 256, 0, stream>>>(w, ksq);
    fb_main<<<131072, 256, 0, stream>>>(x, w, bias, alpha, ksq, out);
    return;
  }

  unsigned short* xpad = (unsigned short*)d_ws;
  unsigned short* wtp  = (unsigned short*)((char*)d_ws + WT_OFF);
  float* spad = (float*)((char*)d_ws + SPAD_OFF);
  float* ksq  = (float*)((char*)d_ws + KSQ_OFF);

  hipMemsetAsync(ksq, 0, 512, stream);
  prep_x<<<17424, 256, 0, stream>>>(x, xpad, spad);
  prep_w<<<128, 256, 0, stream>>>(w, wtp, ksq);
  yat_main<<<2048, 256, 0, stream>>>(xpad, wtp, spad, ksq, bias, alpha, out);
}

// Round 5
// 121.309 us; speedup vs baseline: 1.6080x; 1.5541x over previous
//
#include <hip/hip_runtime.h>
#include <cstdint>
#include <cstddef>

#define CIN   256
#define COUT  128

typedef float  f32x4  __attribute__((ext_vector_type(4)));
typedef __bf16 bf16x8 __attribute__((ext_vector_type(8)));

// ---------------- workspace layout (bytes) ----------------
#define XPAD_BYTES (16ull*66*66*256*2)          // 35,684,352  bf16 padded x
#define WF_OFF     XPAD_BYTES
#define WF_BYTES   (16ull*8*4*128*8*2)          // 1,048,576   bf16 w, frag-ordered
#define SPAD_OFF   (WF_OFF + WF_BYTES)
#define SPAD_BYTES (16ull*66*66*4)              // 278,784     fp32 per-pixel sum(x^2)
#define KSQ_OFF    (SPAD_OFF + SPAD_BYTES)
#define WS_NEEDED  (KSQ_OFF + 512)

__device__ __forceinline__ unsigned short f2bf(float f) {
  unsigned int u = __float_as_uint(f);
  u += 0x7fffu + ((u >> 16) & 1u);              // RNE
  return (unsigned short)(u >> 16);
}

__device__ __forceinline__ void async16(const void* lds, const void* g) {
  __builtin_amdgcn_global_load_lds(
      (const __attribute__((address_space(1))) unsigned int*)g,
      (__attribute__((address_space(3))) unsigned int*)lds, 16, 0, 0);
}

// ---------------- prep: pad+convert x, channel sum of x^2 ----------------
__global__ __launch_bounds__(256) void prep_x(
    const float* __restrict__ x, unsigned short* __restrict__ xpad,
    float* __restrict__ spad)
{
  int wave = threadIdx.x >> 6, lane = threadIdx.x & 63;
  int p = blockIdx.x * 4 + wave;                 // 0..69695 over [16][66][66]
  int b = p / 4356;
  int rem = p - b * 4356;
  int iyp = rem / 66, ixp = rem - iyp * 66;
  bool interior = (iyp >= 1 && iyp <= 64 && ixp >= 1 && ixp <= 64);
  f32x4 v = {0.f, 0.f, 0.f, 0.f};
  if (interior) {
    const float* src = x + (((size_t)b*64 + (iyp-1))*64 + (ixp-1))*CIN + lane*4;
    v = *(const f32x4*)src;
  }
  ushort4 h;
  h.x = f2bf(v.x); h.y = f2bf(v.y); h.z = f2bf(v.z); h.w = f2bf(v.w);
  *(ushort4*)(xpad + (size_t)p*CIN + lane*4) = h;
  float s = v.x*v.x + v.y*v.y + v.z*v.z + v.w*v.w;
  #pragma unroll
  for (int off = 32; off > 0; off >>= 1) s += __shfl_down(s, off);
  if (lane == 0) spad[p] = s;
}

// ---------------- prep: fragment-ordered weights + k_sq ----------------
// wf element index: (((tap*8 + c8)*4 + q)*128 + co)*8 + e, ci = c8*32 + q*8 + e
__global__ __launch_bounds__(256) void prep_w2(
    const float* __restrict__ w, unsigned short* __restrict__ wf,
    float* __restrict__ ksq)
{
  int blk = blockIdx.x;                          // tap*8 + c8
  int tap = blk >> 3, c8 = blk & 7;
  int t = threadIdx.x;
  #pragma unroll
  for (int rr = 0; rr < 2; ++rr) {
    int row = rr*256 + t;                        // 0..511 = q*128 + co
    int q = row >> 7, co = row & 127;
    float s = 0.f;
    union { unsigned short u[8]; uint4 v; } hh;
    #pragma unroll
    for (int e = 0; e < 8; ++e) {
      int ci = c8*32 + q*8 + e;
      float v = w[((size_t)tap*256 + ci)*COUT + co];
      s += v*v;
      hh.u[e] = f2bf(v);
    }
    *(uint4*)(wf + ((size_t)blk*4 + q)*128*8 + (size_t)co*8) = hh.v;
    atomicAdd(ksq + co, s);
  }
}

// ---------------- main fused kernel ----------------
// grid = 2048 (XCD-swizzled): bid -> b = bid>>7, u = (bid>>1)&63, py = bid&1
// block = 256 (4 waves): wave = (px<<1)|coh, wave tile = 64 v x 64 co
// B: coalesced frag loads, half-chunk register double-buffer pinned with
// sched_barrier; barriers are raw s_barrier + counted vmcnt(8) (no drains).
__global__ __launch_bounds__(256, 2) void yat_main(
    const unsigned short* __restrict__ xpad,
    const unsigned short* __restrict__ wf,
    const float* __restrict__ spad,
    const float* __restrict__ ksq,
    const float* __restrict__ bias,
    const float* __restrict__ alpha,
    float* __restrict__ out)
{
  __shared__ __align__(16) unsigned short xs[2][4224];   // 2 x 8448 B
  __shared__ float srow[132];

  int orig = blockIdx.x;
  int bid = (orig & 7) * 256 + (orig >> 3);              // XCD-contiguous
  int py = bid & 1, u = (bid >> 1) & 63, b = bid >> 7;
  int t = threadIdx.x, wave = t >> 6, lane = t & 63;
  int px = wave >> 1, coh = wave & 1;
  int l15 = lane & 15, l4 = lane >> 4;

  if (t < 132) {
    int r = t / 66, c = t - r*66;
    srow[t] = spad[((size_t)b*66 + (u + py) + r)*66 + c];
  }

  const size_t xrow = ((size_t)b*66 + (u + py)) * 66 * CIN;

  // per-thread stage source offsets (chunk-invariant part)
  size_t soff0, soff1, tailoff = 0;
  {
    int s = t;                                   // i = 0
    int a = s / 264; int r2 = s - a*264;
    int q = r2 / 66; int c = r2 - q*66;
    soff0 = xrow + (size_t)(a*66 + c)*CIN + q*8;
    s = 256 + t;                                 // i = 1
    a = s / 264; r2 = s - a*264;
    q = r2 / 66; c = r2 - q*66;
    soff1 = xrow + (size_t)(a*66 + c)*CIN + q*8;
  }
  if (t < 16) {
    int s2 = 248 + t;                            // a = 1 tail segs 512..527
    int q = s2 / 66, c = s2 - q*66;
    tailoff = xrow + (size_t)(66 + c)*CIN + q*8;
  }

  const unsigned short* abase = &xs[0][((size_t)l4*66 + l15 + px)*8];
  // B per-lane base: wf + [l4-group][coh half][l15] (+ py/px tap fold)
  const unsigned short* wb =
      wf + ((size_t)l4*128 + coh*64 + l15)*8 + (size_t)(py*4 + px)*32768;

  f32x4 acc[4][4];
  #pragma unroll
  for (int i = 0; i < 4; ++i)
    #pragma unroll
    for (int j = 0; j < 4; ++j)
      acc[i][j] = (f32x4){0.f, 0.f, 0.f, 0.f};

  bf16x8 B0[2][4], B1[2][4];                     // [bb][nt], a=0 / a=1 banks

  // B frag offset (elements): AA*262144 + bb*65536 + c8*4096 + nt*128
#define LOAD_B(BANK, AA, C8)                                               \
  {                                                                        \
    _Pragma("unroll")                                                      \
    for (int bb = 0; bb < 2; ++bb)                                         \
      _Pragma("unroll")                                                    \
      for (int nt = 0; nt < 4; ++nt)                                       \
        BANK[bb][nt] = *(const bf16x8*)(                                   \
            wb + (size_t)(AA)*262144 + (size_t)bb*65536 +                  \
                 (size_t)(C8)*4096 + nt*128);                              \
  }

#define STAGE_DMA(NB, CI0)                                                 \
  {                                                                        \
    async16(&xs[NB][(size_t)(0*256 + wave*64)*8], xpad + soff0 + (CI0));   \
    async16(&xs[NB][(size_t)(1*256 + wave*64)*8], xpad + soff1 + (CI0));   \
  }

#define COMPUTE_HALF(BUF, AA, BANK)                                        \
  {                                                                        \
    bf16x8 Af[2][4];                                                       \
    _Pragma("unroll")                                                      \
    for (int bb = 0; bb < 2; ++bb)                                         \
      _Pragma("unroll")                                                    \
      for (int mt = 0; mt < 4; ++mt)                                       \
        Af[bb][mt] = *(const bf16x8*)(abase + (size_t)(BUF)*4224 +         \
            (size_t)((AA)*264 + mt*16 + bb)*8);                            \
    __builtin_amdgcn_s_setprio(1);                                         \
    _Pragma("unroll")                                                      \
    for (int bb = 0; bb < 2; ++bb)                                         \
      _Pragma("unroll")                                                    \
      for (int mt = 0; mt < 4; ++mt)                                       \
        _Pragma("unroll")                                                  \
        for (int nt = 0; nt < 4; ++nt)                                     \
          acc[mt][nt] = __builtin_amdgcn_mfma_f32_16x16x32_bf16(           \
              Af[bb][mt], BANK[bb][nt], acc[mt][nt], 0, 0, 0);             \
    __builtin_amdgcn_s_setprio(0);                                         \
  }

  // ---- prologue: stage chunk 0, preload B(a=0, c8=0), one barrier ----
  STAGE_DMA(0, 0);
  uint4 tv;
  if (t < 16) tv = *(const uint4*)(xpad + tailoff);
  LOAD_B(B0, 0, 0);
  if (t < 16) *(uint4*)&xs[0][(size_t)(512 + t)*8] = tv;
  asm volatile("s_waitcnt vmcnt(8) lgkmcnt(0)" ::: "memory");
  __builtin_amdgcn_s_barrier();

  #pragma unroll
  for (int c8 = 0; c8 < 8; ++c8) {
    const int buf = c8 & 1;
    // top: B(a=1) for this chunk; issue next chunk's stage (DMA + tail load)
    LOAD_B(B1, 1, c8);
    if (c8 < 7) {
      STAGE_DMA(buf ^ 1, (c8 + 1) * 32);
      if (t < 16) tv = *(const uint4*)(xpad + tailoff + (c8 + 1) * 32);
    }
    __builtin_amdgcn_sched_barrier(0);
    // a = 0 (uses B0 loaded one chunk ago)
    COMPUTE_HALF(buf, 0, B0);
    if (c8 < 7) LOAD_B(B0, 0, c8 + 1);
    __builtin_amdgcn_sched_barrier(0);
    // a = 1 (uses B1 loaded at top, covered by a=0 compute)
    COMPUTE_HALF(buf, 1, B1);
    if (c8 < 7) {
      if (t < 16) *(uint4*)&xs[buf ^ 1][(size_t)(512 + t)*8] = tv;
      // stages+tail retired; 8 B0-prefetch loads stay in flight
      asm volatile("s_waitcnt vmcnt(8) lgkmcnt(0)" ::: "memory");
      __builtin_amdgcn_s_barrier();
    }
  }

#undef LOAD_B
#undef STAGE_DMA
#undef COMPUTE_HALF

  // ---------------- epilogue ----------------
  float scale = powf(sqrtf(128.f) / log1pf(128.f), alpha[0]);
  int oy = 2*u + py;
  float kq[4], bi[4];
  #pragma unroll
  for (int nt = 0; nt < 4; ++nt) {
    int n = coh*64 + nt*16 + l15;
    kq[nt] = ksq[n]; bi[nt] = bias[n];
  }
  size_t orow = ((size_t)b*128 + oy) * 128 * COUT;
  #pragma unroll
  for (int mt = 0; mt < 4; ++mt) {
    #pragma unroll
    for (int r = 0; r < 4; ++r) {
      int v = mt*16 + l4*4 + r;
      float ps = srow[v+px] + srow[v+px+1] + srow[66 + v+px] + srow[66 + v+px+1];
      #pragma unroll
      for (int nt = 0; nt < 4; ++nt) {
        float dot = acc[mt][nt][r];
        float dist = ps + kq[nt] - 2.f*dot + 1e-5f;
        float y = (dot*dot/dist + bi[nt]) * scale;
        int n = coh*64 + nt*16 + l15;
        out[orow + (size_t)(2*v + px)*COUT + n] = y;
      }
    }
  }
}

// ---------------- fallback (tiny ws): direct fp32 ----------------
__global__ __launch_bounds__(256) void fb_ksq(const float* __restrict__ w,
                                              float* __restrict__ ksq) {
  __shared__ float red[256];
  int co = blockIdx.x, t = threadIdx.x;
  float s = 0.f;
  for (int j = t; j < 4096; j += 256) { float v = w[(size_t)j*COUT + co]; s += v*v; }
  red[t] = s; __syncthreads();
  for (int off = 128; off > 0; off >>= 1) {
    if (t < off) red[t] += red[t + off];
    __syncthreads();
  }
  if (t == 0) ksq[co] = red[0];
}

__global__ __launch_bounds__(256) void fb_main(
    const float* __restrict__ x, const float* __restrict__ w,
    const float* __restrict__ bias, const float* __restrict__ alpha,
    const float* __restrict__ ksq, float* __restrict__ out)
{
  size_t idx = (size_t)blockIdx.x * 256 + threadIdx.x;
  int co = (int)(idx & 127);
  int ox = (int)((idx >> 7) & 127);
  int oy = (int)((idx >> 14) & 127);
  int b  = (int)(idx >> 21);
  int py = oy & 1, px = ox & 1, u = oy >> 1, v = ox >> 1;
  float dot = 0.f, ps = 0.f;
  for (int a = 0; a < 2; ++a) {
    int iy = u + py + a - 1;
    if (iy < 0 || iy > 63) continue;
    for (int b2 = 0; b2 < 2; ++b2) {
      int ix = v + px + b2 - 1;
      if (ix < 0 || ix > 63) continue;
      const float* xp = x + (((size_t)b*64 + iy)*64 + ix)*CIN;
      const float* wp = w + ((size_t)((py + 2*a)*4 + (px + 2*b2))*CIN)*COUT + co;
      for (int ci = 0; ci < CIN; ++ci) {
        float xv = xp[ci];
        dot += xv * wp[(size_t)ci*COUT];
        ps  += xv * xv;
      }
    }
  }
  float dist = ps + ksq[co] - 2.f*dot + 1e-5f;
  float scale = powf(sqrtf(128.f) / log1pf(128.f), alpha[0]);
  out[idx] = (dot*dot/dist + bias[co]) * scale;
}

// ---------------- launcher ----------------
extern "C" void kernel_launch(void* const* d_in, const int* in_sizes, int n_in,
                              void* d_out, int out_size, void* d_ws, size_t ws_size,
                              hipStream_t stream)
{
  const float* x     = (const float*)d_in[0];
  const float* w     = (const float*)d_in[1];
  const float* bias  = (const float*)d_in[2];
  const float* alpha = (const float*)d_in[3];
  float* out = (float*)d_out;

  if (ws_size < WS_NEEDED) {
    float* ksq = (float*)d_ws;
    fb_ksq<<<128, 256, 0, stream>>>(w, ksq);
    fb_main<<<131072, 256, 0, stream>>>(x, w, bias, alpha, ksq, out);
    return;
  }

  unsigned short* xpad = (unsigned short*)d_ws;
  unsigned short* wfp  = (unsigned short*)((char*)d_ws + WF_OFF);
  float* spad = (float*)((char*)d_ws + SPAD_OFF);
  float* ksq  = (float*)((char*)d_ws + KSQ_OFF);

  hipMemsetAsync(ksq, 0, 512, stream);
  prep_x<<<17424, 256, 0, stream>>>(x, xpad, spad);
  prep_w2<<<128, 256, 0, stream>>>(w, wfp, ksq);
  yat_main<<<2048, 256, 0, stream>>>(xpad, wfp, spad, ksq, bias, alpha, out);
}